// Round 1
// baseline (347.811 us; speedup 1.0000x reference)
//
#include <hip/hip_runtime.h>

typedef unsigned short u16;
typedef unsigned int u32;
typedef __attribute__((ext_vector_type(8))) short bf16x8;
typedef __attribute__((ext_vector_type(4))) float f32x4;

#define D_MODEL 1024
#define NHEAD 16
#define DHEAD 64
#define SEQ 2048
#define BATCH 4
#define MTOT (BATCH * SEQ) /* 8192 */

#define MFMA16(A, B, C) __builtin_amdgcn_mfma_f32_16x16x32_bf16((A), (B), (C), 0, 0, 0)

__device__ __forceinline__ u16 f2bf(float f) {
  u32 u = __builtin_bit_cast(u32, f);
  u = (u + 0x7FFFu + ((u >> 16) & 1u)) >> 16;
  return (u16)u;
}
__device__ __forceinline__ float bf2f(u16 h) {
  u32 u = ((u32)h) << 16;
  return __builtin_bit_cast(float, u);
}

// async global->LDS, 16B per lane. lds must be wave-uniform; g is per-lane.
__device__ __forceinline__ void async_copy16(void* lds, const void* g) {
  __builtin_amdgcn_global_load_lds(
      (const __attribute__((address_space(1))) u32*)g,
      (__attribute__((address_space(3))) u32*)lds, 16, 0, 0);
}

// ---------------- fp32 -> bf16 convert ----------------
__global__ void cvt_f32_bf16(const float* __restrict__ s, u16* __restrict__ d, int n4) {
  int i = blockIdx.x * blockDim.x + threadIdx.x;
  int st = gridDim.x * blockDim.x;
  for (; i < n4; i += st) {
    float4 v = ((const float4*)s)[i];
    ushort4 o;
    o.x = f2bf(v.x); o.y = f2bf(v.y); o.z = f2bf(v.z); o.w = f2bf(v.w);
    ((ushort4*)d)[i] = o;
  }
}

// ---------------- NT GEMM: C[m][n] = sum_k A[m][k]*B[n][k] + bias[n] ----------------
// 128x128 tile, BK=64, global_load_lds w/ XOR-swizzled source, swizzled ds_read_b128.
// SM: 0 = bf16 row-major out, 1 = f32 row-major out, 2 = bf16 transposed V out
#define BM 128
#define BN 128
#define BKG 64

template <int SM>
__global__ __launch_bounds__(256, 2) void gemm_bt(const u16* __restrict__ A,
                                                  const u16* __restrict__ Bw,
                                                  const float* __restrict__ bias,
                                                  void* __restrict__ Cout,
                                                  int M, int N, int K) {
  __shared__ u16 As[BM * BKG]; // 16KB, rows 128B, granule-swizzled g^=(row&7)
  __shared__ u16 Bs[BN * BKG]; // 16KB
  const int tid = threadIdx.x;
  const int l = tid & 63;
  const int wid = tid >> 6;
  // XCD-aware swizzle (nwg % 8 == 0 here)
  const int nwg = gridDim.x;
  const int bid = blockIdx.x;
  const int cpx = nwg >> 3;
  const int swz = (bid & 7) * cpx + (bid >> 3);
  const int ntile = N / BN;
  const int m0 = (swz / ntile) * BM;
  const int n0 = (swz % ntile) * BN;
  const int wr = wid >> 1, wc = wid & 1;
  const int r = l & 15, kg = l >> 4;
  f32x4 acc[4][4] = {};
  char* AsB = (char*)As;
  char* BsB = (char*)Bs;
  const int arow = l >> 3;               // row within 8-row chunk
  const int agran = (l & 7) ^ arow;      // inverse-swizzled source granule

  for (int kt = 0; kt < K; kt += BKG) {
#pragma unroll
    for (int cc = 0; cc < 4; ++cc) {
      int c = wid + (cc << 2);           // chunk 0..15 (1KB = 8 rows x 128B)
      int rowi = (c << 3) + arow;
      const char* ga = (const char*)A + ((size_t)(m0 + rowi) * K + kt) * 2 + agran * 16;
      async_copy16(AsB + c * 1024, ga);
      const char* gb = (const char*)Bw + ((size_t)(n0 + rowi) * K + kt) * 2 + agran * 16;
      async_copy16(BsB + c * 1024, gb);
    }
    __syncthreads();
#pragma unroll
    for (int half = 0; half < 2; ++half) {
      const int g = ((half << 2) + kg) ^ (r & 7);
      bf16x8 af[4], bf[4];
#pragma unroll
      for (int i = 0; i < 4; ++i) {
        af[i] = *(const bf16x8*)(AsB + (wr * 64 + i * 16 + r) * 128 + g * 16);
        bf[i] = *(const bf16x8*)(BsB + (wc * 64 + i * 16 + r) * 128 + g * 16);
      }
#pragma unroll
      for (int i = 0; i < 4; ++i)
#pragma unroll
        for (int j = 0; j < 4; ++j)
          acc[i][j] = MFMA16(af[i], bf[j], acc[i][j]);
    }
    __syncthreads();
  }
  // epilogue: C row = (lane>>4)*4 + reg, col = lane&15 within each 16x16 frag
#pragma unroll
  for (int i = 0; i < 4; ++i) {
#pragma unroll
    for (int j = 0; j < 4; ++j) {
      const int col = n0 + wc * 64 + j * 16 + r;
      const float bv = bias[col];
      const int row0 = m0 + wr * 64 + i * 16 + kg * 4;
      if (SM == 0) {
        u16* C = (u16*)Cout;
#pragma unroll
        for (int jj = 0; jj < 4; ++jj)
          C[(size_t)(row0 + jj) * N + col] = f2bf(acc[i][j][jj] + bv);
      } else if (SM == 1) {
        float* C = (float*)Cout;
#pragma unroll
        for (int jj = 0; jj < 4; ++jj)
          C[(size_t)(row0 + jj) * N + col] = acc[i][j][jj] + bv;
      } else {
        // V transposed store: Vt[(b*16+h)*64 + dh][tok], 4 consecutive tok per lane
        u16* C = (u16*)Cout;
        const int hh = col >> 6, dh = col & 63;
        const int bb = row0 >> 11, tok = row0 & 2047;
        ushort4 o;
        o.x = f2bf(acc[i][j][0] + bv);
        o.y = f2bf(acc[i][j][1] + bv);
        o.z = f2bf(acc[i][j][2] + bv);
        o.w = f2bf(acc[i][j][3] + bv);
        *(ushort4*)(C + ((size_t)((bb * 16 + hh) * 64 + dh) * SEQ + tok)) = o;
      }
    }
  }
}

// ---------------- QK norm: v /= (||v||_2 + 1e-6) per 64-elem head vector ----------------
__global__ void qknorm(u16* __restrict__ Q, int nchunk) {
  const int l = threadIdx.x & 63;
  int w = (blockIdx.x * blockDim.x + threadIdx.x) >> 6;
  const int nw = (gridDim.x * blockDim.x) >> 6;
  for (int c = w; c < nchunk; c += nw) {
    size_t base = (size_t)c * 64 + l;
    float v = bf2f(Q[base]);
    float s = v * v;
#pragma unroll
    for (int m = 1; m < 64; m <<= 1) s += __shfl_xor(s, m, 64);
    Q[base] = f2bf(v / (sqrtf(s) + 1e-6f));
  }
}

// ---------------- flash attention ----------------
// block = 4 waves, each wave owns 32 q-rows (QBLK=128). KVB=128 per tile.
// K staged [kv][64] (128B rows, g^=(row&7)); Vt staged [dh][KVB] (256B rows, g^=(row&15));
// P round-trips through per-wave LDS [16][KVB] (256B rows, g^=(row&15)).
#define KVB 128

__global__ __launch_bounds__(256, 2) void attn_kernel(const u16* __restrict__ Q,
                                                      const u16* __restrict__ K,
                                                      const u16* __restrict__ Vt,
                                                      u16* __restrict__ O) {
  __shared__ u16 Ks[KVB * 64];     // 16KB
  __shared__ u16 Vs[64 * KVB];     // 16KB
  __shared__ u16 Ps[4 * 16 * KVB]; // 16KB (per-wave 4KB)
  const int tid = threadIdx.x;
  const int l = tid & 63;
  const int wid = tid >> 6;
  const int r = l & 15, kg = l >> 4;
  const int qt = blockIdx.x;  // 0..15
  const int bh = blockIdx.y;  // 0..63
  const int b = bh >> 4, h = bh & 15;
  char* KsB = (char*)Ks;
  char* VsB = (char*)Vs;
  char* PsB = (char*)Ps + wid * (16 * KVB * 2);

  // Q fragments in registers (rows wid*32 + mi*16 + r, k-slices of DH=64)
  bf16x8 qf[2][2];
  {
    const u16* q0 = Q + ((size_t)(b * SEQ + qt * 128 + wid * 32 + r)) * D_MODEL + h * 64;
    qf[0][0] = *(const bf16x8*)(q0 + kg * 8);
    qf[0][1] = *(const bf16x8*)(q0 + 32 + kg * 8);
    qf[1][0] = *(const bf16x8*)(q0 + 16 * D_MODEL + kg * 8);
    qf[1][1] = *(const bf16x8*)(q0 + 16 * D_MODEL + 32 + kg * 8);
  }
  const f32x4 fz = {0.f, 0.f, 0.f, 0.f};
  float mrun[2][4], lrun[2][4];
  f32x4 oacc[2][4];
#pragma unroll
  for (int mi = 0; mi < 2; ++mi)
#pragma unroll
    for (int f = 0; f < 4; ++f) oacc[mi][f] = fz;
#pragma unroll
  for (int mi = 0; mi < 2; ++mi)
#pragma unroll
    for (int j = 0; j < 4; ++j) {
      mrun[mi][j] = -__builtin_inff();
      lrun[mi][j] = 0.f;
    }
  const int srow = l >> 3;
  const int sg7 = (l & 7) ^ srow;

  for (int t = 0; t < SEQ / KVB; ++t) {
    const int kv0 = t * KVB;
#pragma unroll
    for (int cc = 0; cc < 4; ++cc) {
      int c = wid + (cc << 2); // 0..15
      {
        int row = (c << 3) + srow; // kv row 0..127
        const char* g = (const char*)K +
                        ((size_t)(b * SEQ + kv0 + row) * D_MODEL + h * 64) * 2 + sg7 * 16;
        async_copy16(KsB + c * 1024, g);
      }
      {
        int row = (c << 2) + kg; // dh row 0..63 (4 rows per 1KB chunk)
        int gr = (l & 15) ^ (row & 15);
        const char* g = (const char*)Vt +
                        ((size_t)(bh * 64 + row) * SEQ + kv0) * 2 + gr * 16;
        async_copy16(VsB + c * 1024, g);
      }
    }
    __syncthreads();

    // S = Q K^T  (both mi share the K fragment reads)
    f32x4 s[2][8];
#pragma unroll
    for (int mi = 0; mi < 2; ++mi)
#pragma unroll
      for (int f = 0; f < 8; ++f) s[mi][f] = fz;
#pragma unroll
    for (int f = 0; f < 8; ++f) {
      const int rowK = f * 16 + r;
      const int g0 = kg ^ (r & 7);
      const int g1 = (4 + kg) ^ (r & 7);
      bf16x8 kf0 = *(const bf16x8*)(KsB + rowK * 128 + g0 * 16);
      bf16x8 kf1 = *(const bf16x8*)(KsB + rowK * 128 + g1 * 16);
      s[0][f] = MFMA16(qf[0][0], kf0, s[0][f]);
      s[0][f] = MFMA16(qf[0][1], kf1, s[0][f]);
      s[1][f] = MFMA16(qf[1][0], kf0, s[1][f]);
      s[1][f] = MFMA16(qf[1][1], kf1, s[1][f]);
    }

#pragma unroll
    for (int mi = 0; mi < 2; ++mi) {
      float rmax[4], rsum[4], scj[4];
#pragma unroll
      for (int j = 0; j < 4; ++j) {
        float v = s[mi][0][j];
#pragma unroll
        for (int f = 1; f < 8; ++f) v = fmaxf(v, s[mi][f][j]);
        v = fmaxf(v, __shfl_xor(v, 1));
        v = fmaxf(v, __shfl_xor(v, 2));
        v = fmaxf(v, __shfl_xor(v, 4));
        v = fmaxf(v, __shfl_xor(v, 8));
        rmax[j] = v;
      }
#pragma unroll
      for (int j = 0; j < 4; ++j) {
        float mn = fmaxf(mrun[mi][j], rmax[j]);
        scj[j] = __expf(mrun[mi][j] - mn);
        mrun[mi][j] = mn;
        rsum[j] = 0.f;
      }
      // P = exp(S - m), stash bf16 into per-wave LDS (swizzled)
#pragma unroll
      for (int f = 0; f < 8; ++f) {
#pragma unroll
        for (int j = 0; j < 4; ++j) {
          float p = __expf(s[mi][f][j] - mrun[mi][j]);
          rsum[j] += p;
          int row = kg * 4 + j;
          int gr = (f * 2 + (r >> 3)) ^ row;
          ((u16*)PsB)[row * KVB + gr * 8 + (r & 7)] = f2bf(p);
        }
      }
#pragma unroll
      for (int j = 0; j < 4; ++j) {
        float v = rsum[j];
        v += __shfl_xor(v, 1);
        v += __shfl_xor(v, 2);
        v += __shfl_xor(v, 4);
        v += __shfl_xor(v, 8);
        lrun[mi][j] = lrun[mi][j] * scj[j] + v;
      }
#pragma unroll
      for (int f = 0; f < 4; ++f)
#pragma unroll
        for (int j = 0; j < 4; ++j) oacc[mi][f][j] *= scj[j];
      // O += P V   (A-frag P from LDS, B-frag from Vt tile)
#pragma unroll
      for (int ks = 0; ks < 4; ++ks) {
        const int gp = (ks * 4 + kg) ^ r;
        bf16x8 pf = *(const bf16x8*)(PsB + (r * KVB + gp * 8) * 2);
#pragma unroll
        for (int f = 0; f < 4; ++f) {
          const int rowV = f * 16 + r;
          const int gv = (ks * 4 + kg) ^ r; // rowV & 15 == r
          bf16x8 vf = *(const bf16x8*)(VsB + rowV * 256 + gv * 16);
          oacc[mi][f] = MFMA16(pf, vf, oacc[mi][f]);
        }
      }
    }
    __syncthreads();
  }
  // epilogue: divide by softmax denom, store bf16
#pragma unroll
  for (int mi = 0; mi < 2; ++mi) {
    const int qrow = qt * 128 + wid * 32 + mi * 16 + kg * 4;
#pragma unroll
    for (int f = 0; f < 4; ++f) {
#pragma unroll
      for (int j = 0; j < 4; ++j) {
        O[((size_t)(b * SEQ + qrow + j)) * D_MODEL + h * 64 + f * 16 + r] =
            f2bf(oacc[mi][f][j] / lrun[mi][j]);
      }
    }
  }
}

// ---------------- launch ----------------
extern "C" void kernel_launch(void* const* d_in, const int* in_sizes, int n_in,
                              void* d_out, int out_size, void* d_ws, size_t ws_size,
                              hipStream_t stream) {
  const float* x   = (const float*)d_in[0];
  const float* ctx = (const float*)d_in[1];
  const float* Wq  = (const float*)d_in[2];
  const float* bq  = (const float*)d_in[3];
  const float* Wk  = (const float*)d_in[4];
  const float* bk  = (const float*)d_in[5];
  const float* Wv  = (const float*)d_in[6];
  const float* bv  = (const float*)d_in[7];
  const float* Wo  = (const float*)d_in[8];
  const float* bo  = (const float*)d_in[9];
  float* out = (float*)d_out;

  const size_t NTOK = (size_t)MTOT * D_MODEL; // 8M elems
  const size_t WSZ = (size_t)D_MODEL * D_MODEL;
  u16* xb  = (u16*)d_ws;       // x bf16; later reused as attention output
  u16* cb  = xb + NTOK;
  u16* wqb = cb + NTOK;
  u16* wkb = wqb + WSZ;
  u16* wvb = wkb + WSZ;
  u16* wob = wvb + WSZ;
  u16* Qb  = wob + WSZ;
  u16* Kb  = Qb + NTOK;
  u16* Vtb = Kb + NTOK;        // [b*16+h][dh][tok]
  (void)in_sizes; (void)n_in; (void)out_size; (void)ws_size;

  dim3 blk(256);
  cvt_f32_bf16<<<2048, blk, 0, stream>>>(x, xb, (int)(NTOK / 4));
  cvt_f32_bf16<<<2048, blk, 0, stream>>>(ctx, cb, (int)(NTOK / 4));
  cvt_f32_bf16<<<512, blk, 0, stream>>>(Wq, wqb, (int)(WSZ / 4));
  cvt_f32_bf16<<<512, blk, 0, stream>>>(Wk, wkb, (int)(WSZ / 4));
  cvt_f32_bf16<<<512, blk, 0, stream>>>(Wv, wvb, (int)(WSZ / 4));
  cvt_f32_bf16<<<512, blk, 0, stream>>>(Wo, wob, (int)(WSZ / 4));

  gemm_bt<0><<<512, blk, 0, stream>>>(xb, wqb, bq, Qb, MTOT, D_MODEL, D_MODEL);
  gemm_bt<0><<<512, blk, 0, stream>>>(cb, wkb, bk, Kb, MTOT, D_MODEL, D_MODEL);
  gemm_bt<2><<<512, blk, 0, stream>>>(cb, wvb, bv, Vtb, MTOT, D_MODEL, D_MODEL);

  qknorm<<<1024, blk, 0, stream>>>(Qb, MTOT * NHEAD);
  qknorm<<<1024, blk, 0, stream>>>(Kb, MTOT * NHEAD);

  attn_kernel<<<dim3(16, 64), blk, 0, stream>>>(Qb, Kb, Vtb, xb);

  gemm_bt<1><<<512, blk, 0, stream>>>(xb, wob, bo, out, MTOT, D_MODEL, D_MODEL);
}

// Round 2
// 251.423 us; speedup vs baseline: 1.3834x; 1.3834x over previous
//
#include <hip/hip_runtime.h>

typedef unsigned short u16;
typedef unsigned int u32;
typedef __attribute__((ext_vector_type(8))) short bf16x8;
typedef __attribute__((ext_vector_type(4))) float f32x4;
typedef __attribute__((ext_vector_type(16))) float f32x16;
typedef __attribute__((ext_vector_type(4))) u32 u32x4;

#define D_MODEL 1024
#define NHEAD 16
#define DHEAD 64
#define SEQ 2048
#define BATCH 4
#define MTOT (BATCH * SEQ) /* 8192 */

#define MFMA16(A, B, C) __builtin_amdgcn_mfma_f32_16x16x32_bf16((A), (B), (C), 0, 0, 0)
#define MFMA32(A, B, C) __builtin_amdgcn_mfma_f32_32x32x16_bf16((A), (B), (C), 0, 0, 0)

__device__ __forceinline__ u16 f2bf(float f) {
  u32 u = __builtin_bit_cast(u32, f);
  u = (u + 0x7FFFu + ((u >> 16) & 1u)) >> 16;
  return (u16)u;
}
__device__ __forceinline__ float bf2f(u16 h) {
  u32 u = ((u32)h) << 16;
  return __builtin_bit_cast(float, u);
}

// async global->LDS, 16B per lane. lds must be wave-uniform; g is per-lane.
__device__ __forceinline__ void async_copy16(void* lds, const void* g) {
  __builtin_amdgcn_global_load_lds(
      (const __attribute__((address_space(1))) u32*)g,
      (__attribute__((address_space(3))) u32*)lds, 16, 0, 0);
}

__device__ __forceinline__ u32 cvtpk_bf16(float lo, float hi) {
  u32 r;
  asm("v_cvt_pk_bf16_f32 %0, %1, %2" : "=v"(r) : "v"(lo), "v"(hi));
  return r;
}
// swaps a.hi32lanes <-> b.lo32lanes
__device__ __forceinline__ void permswap(u32& a, u32& b) {
  asm("v_permlane32_swap_b32 %0, %1" : "+v"(a), "+v"(b));
}

// ---------------- fp32 -> bf16 convert ----------------
__global__ void cvt_f32_bf16(const float* __restrict__ s, u16* __restrict__ d, int n4) {
  int i = blockIdx.x * blockDim.x + threadIdx.x;
  int st = gridDim.x * blockDim.x;
  for (; i < n4; i += st) {
    float4 v = ((const float4*)s)[i];
    ushort4 o;
    o.x = f2bf(v.x); o.y = f2bf(v.y); o.z = f2bf(v.z); o.w = f2bf(v.w);
    ((ushort4*)d)[i] = o;
  }
}

// ---------------- NT GEMM: C[m][n] = sum_k A[m][k]*B[n][k] + bias[n] ----------------
#define BM 128
#define BN 128
#define BKG 64

template <int SM>
__global__ __launch_bounds__(256, 2) void gemm_bt(const u16* __restrict__ A,
                                                  const u16* __restrict__ Bw,
                                                  const float* __restrict__ bias,
                                                  void* __restrict__ Cout,
                                                  int M, int N, int K) {
  __shared__ u16 As[BM * BKG]; // 16KB, rows 128B, granule-swizzled g^=(row&7)
  __shared__ u16 Bs[BN * BKG]; // 16KB
  const int tid = threadIdx.x;
  const int l = tid & 63;
  const int wid = tid >> 6;
  const int nwg = gridDim.x;
  const int bid = blockIdx.x;
  const int cpx = nwg >> 3;
  const int swz = (bid & 7) * cpx + (bid >> 3);
  const int ntile = N / BN;
  const int m0 = (swz / ntile) * BM;
  const int n0 = (swz % ntile) * BN;
  const int wr = wid >> 1, wc = wid & 1;
  const int r = l & 15, kg = l >> 4;
  f32x4 acc[4][4] = {};
  char* AsB = (char*)As;
  char* BsB = (char*)Bs;
  const int arow = l >> 3;
  const int agran = (l & 7) ^ arow;

  for (int kt = 0; kt < K; kt += BKG) {
#pragma unroll
    for (int cc = 0; cc < 4; ++cc) {
      int c = wid + (cc << 2);
      int rowi = (c << 3) + arow;
      const char* ga = (const char*)A + ((size_t)(m0 + rowi) * K + kt) * 2 + agran * 16;
      async_copy16(AsB + c * 1024, ga);
      const char* gb = (const char*)Bw + ((size_t)(n0 + rowi) * K + kt) * 2 + agran * 16;
      async_copy16(BsB + c * 1024, gb);
    }
    __syncthreads();
#pragma unroll
    for (int half = 0; half < 2; ++half) {
      const int g = ((half << 2) + kg) ^ (r & 7);
      bf16x8 af[4], bf[4];
#pragma unroll
      for (int i = 0; i < 4; ++i) {
        af[i] = *(const bf16x8*)(AsB + (wr * 64 + i * 16 + r) * 128 + g * 16);
        bf[i] = *(const bf16x8*)(BsB + (wc * 64 + i * 16 + r) * 128 + g * 16);
      }
#pragma unroll
      for (int i = 0; i < 4; ++i)
#pragma unroll
        for (int j = 0; j < 4; ++j)
          acc[i][j] = MFMA16(af[i], bf[j], acc[i][j]);
    }
    __syncthreads();
  }
#pragma unroll
  for (int i = 0; i < 4; ++i) {
#pragma unroll
    for (int j = 0; j < 4; ++j) {
      const int col = n0 + wc * 64 + j * 16 + r;
      const float bv = bias[col];
      const int row0 = m0 + wr * 64 + i * 16 + kg * 4;
      if (SM == 0) {
        u16* C = (u16*)Cout;
#pragma unroll
        for (int jj = 0; jj < 4; ++jj)
          C[(size_t)(row0 + jj) * N + col] = f2bf(acc[i][j][jj] + bv);
      } else if (SM == 1) {
        float* C = (float*)Cout;
#pragma unroll
        for (int jj = 0; jj < 4; ++jj)
          C[(size_t)(row0 + jj) * N + col] = acc[i][j][jj] + bv;
      } else {
        u16* C = (u16*)Cout;
        const int hh = col >> 6, dh = col & 63;
        const int bb = row0 >> 11, tok = row0 & 2047;
        ushort4 o;
        o.x = f2bf(acc[i][j][0] + bv);
        o.y = f2bf(acc[i][j][1] + bv);
        o.z = f2bf(acc[i][j][2] + bv);
        o.w = f2bf(acc[i][j][3] + bv);
        *(ushort4*)(C + ((size_t)((bb * 16 + hh) * 64 + dh) * SEQ + tok)) = o;
      }
    }
  }
}

// ---------------- QK norm ----------------
__global__ void qknorm(u16* __restrict__ Q, int nchunk) {
  const int l = threadIdx.x & 63;
  int w = (blockIdx.x * blockDim.x + threadIdx.x) >> 6;
  const int nw = (gridDim.x * blockDim.x) >> 6;
  for (int c = w; c < nchunk; c += nw) {
    size_t base = (size_t)c * 64 + l;
    float v = bf2f(Q[base]);
    float s = v * v;
#pragma unroll
    for (int m = 1; m < 64; m <<= 1) s += __shfl_xor(s, m, 64);
    Q[base] = f2bf(v / (sqrtf(s) + 1e-6f));
  }
}

// ---------------- flash attention v2: swapped 32x32, in-register softmax ----------------
// block = 4 waves; wave owns 32 q rows (1 per lane-pair), KVB=128 per tile.
// After qk-norm, S in [-1,1]: fixed softmax max = 1 (shift-invariant) -> no max
// tracking, no rescale. S^T = mfma32(Kfrag, Qfrag) keeps each q-row lane-local.
// P built in-register via v_cvt_pk_bf16_f32 + v_permlane32_swap_b32 (T12).
// K LDS [128][64] rows 128B swz g^=(row&7); Vt LDS [64][128] rows 256B swz g^=(row&15).
// Double-buffered staging, one barrier per tile.
#define KVB 128

__global__ __launch_bounds__(256, 2) void attn_kernel(const u16* __restrict__ Q,
                                                      const u16* __restrict__ K,
                                                      const u16* __restrict__ Vt,
                                                      u16* __restrict__ O) {
  __shared__ alignas(16) u16 Ks[2][KVB * 64]; // 2 x 16KB
  __shared__ alignas(16) u16 Vs[2][64 * KVB]; // 2 x 16KB
  const int tid = threadIdx.x;
  const int l = tid & 63;
  const int wid = tid >> 6;
  const int qg = l & 31;     // q row within wave
  const int half = l >> 5;
  const int r16 = l & 15, kg = l >> 4;
  const int qt = blockIdx.x; // 0..15
  const int bh = blockIdx.y; // 0..63
  const int b = bh >> 4, h = bh & 15;
  const int srow = l >> 3;
  const int sg7 = (l & 7) ^ srow;

  // Q fragments: B-operand, col=q=l&31, k = dc*16 + half*8 + e
  bf16x8 qf[4];
  {
    const u16* q0 = Q + ((size_t)(b * SEQ + qt * 128 + wid * 32 + qg)) * D_MODEL + h * 64 + half * 8;
#pragma unroll
    for (int dc = 0; dc < 4; ++dc) qf[dc] = *(const bf16x8*)(q0 + dc * 16);
  }
  f32x16 oacc[2] = {};
  float lrun = 0.f;

  auto stage = [&](int bufi, int t) {
    const int kv0 = t * KVB;
    char* KsB = (char*)Ks[bufi];
    char* VsB = (char*)Vs[bufi];
#pragma unroll
    for (int cc = 0; cc < 4; ++cc) {
      int c = wid + (cc << 2);
      {
        int row = (c << 3) + srow;
        const char* g = (const char*)K +
                        ((size_t)(b * SEQ + kv0 + row) * D_MODEL + h * 64) * 2 + sg7 * 16;
        async_copy16(KsB + c * 1024, g);
      }
      {
        int row = (c << 2) + kg;
        int gr = r16 ^ (row & 15);
        const char* g = (const char*)Vt +
                        ((size_t)(bh * 64 + row) * SEQ + kv0) * 2 + gr * 16;
        async_copy16(VsB + c * 1024, g);
      }
    }
  };

  stage(0, 0);
  __syncthreads();
  int buf = 0;

  for (int t = 0; t < SEQ / KVB; ++t) {
    if (t + 1 < SEQ / KVB) stage(buf ^ 1, t + 1);
    const char* KsB = (const char*)Ks[buf];
    const char* VsB = (const char*)Vs[buf];

    // S^T[kv][q]: 4 tiles of 32 kv; lane holds q=l&31, kv=(reg&3)+8*(reg>>2)+4*half (+32*t32)
    f32x16 st[4] = {};
#pragma unroll
    for (int t32 = 0; t32 < 4; ++t32) {
      const int rowK = t32 * 32 + qg;
      const int swzK = l & 7; // rowK & 7
#pragma unroll
      for (int dc = 0; dc < 4; ++dc) {
        const int g = (dc * 2 + half) ^ swzK;
        bf16x8 kf = *(const bf16x8*)(KsB + rowK * 128 + g * 16);
        st[t32] = MFMA32(kf, qf[dc], st[t32]);
      }
    }
    // softmax with fixed max = 1: p = exp(s - 1)
    float rs = 0.f;
#pragma unroll
    for (int t32 = 0; t32 < 4; ++t32)
#pragma unroll
      for (int rr = 0; rr < 16; ++rr) {
        float p = __expf(st[t32][rr] - 1.0f);
        rs += p;
        st[t32][rr] = p;
      }
    lrun += rs;
    // PV: O^T[dh][q] += V^T[dh][kv] * P[q][kv]
#pragma unroll
    for (int t32 = 0; t32 < 4; ++t32) {
#pragma unroll
      for (int cc = 0; cc < 2; ++cc) {
        const int base = cc * 8;
        u32 wA = cvtpk_bf16(st[t32][base + 0], st[t32][base + 1]);
        u32 wB = cvtpk_bf16(st[t32][base + 2], st[t32][base + 3]);
        u32 wC = cvtpk_bf16(st[t32][base + 4], st[t32][base + 5]);
        u32 wD = cvtpk_bf16(st[t32][base + 6], st[t32][base + 7]);
        permswap(wA, wC); // wA = {lo:kv(0,1)+..., hi:kv(8,9)}, wC = {lo:kv(4,5), hi:kv(12,13)}
        permswap(wB, wD);
        u32x4 pw = {wA, wB, wC, wD};
        bf16x8 pf = __builtin_bit_cast(bf16x8, pw);
        const int c = t32 * 2 + cc; // kv chunk of 16
#pragma unroll
        for (int dt = 0; dt < 2; ++dt) {
          const int rowV = dt * 32 + qg;
          const int gv = (c * 2 + half) ^ r16; // rowV & 15 == l & 15
          bf16x8 vf = *(const bf16x8*)(VsB + rowV * 256 + gv * 16);
          oacc[dt] = MFMA32(vf, pf, oacc[dt]);
        }
      }
    }
    __syncthreads();
    buf ^= 1;
  }

  // epilogue: denom = own-half sum + other-half sum; pack pairs, u32 stores
  lrun += __shfl_xor(lrun, 32);
  const float inv = 1.0f / lrun;
  u32* orow = (u32*)(O + ((size_t)(b * SEQ + qt * 128 + wid * 32 + qg)) * D_MODEL + h * 64);
#pragma unroll
  for (int dt = 0; dt < 2; ++dt)
#pragma unroll
    for (int w = 0; w < 8; ++w) {
      const int dh = dt * 32 + (w & 1) * 2 + 8 * (w >> 1) + 4 * half;
      u32 pk = cvtpk_bf16(oacc[dt][2 * w] * inv, oacc[dt][2 * w + 1] * inv);
      orow[dh >> 1] = pk;
    }
}

// ---------------- launch ----------------
extern "C" void kernel_launch(void* const* d_in, const int* in_sizes, int n_in,
                              void* d_out, int out_size, void* d_ws, size_t ws_size,
                              hipStream_t stream) {
  const float* x   = (const float*)d_in[0];
  const float* ctx = (const float*)d_in[1];
  const float* Wq  = (const float*)d_in[2];
  const float* bq  = (const float*)d_in[3];
  const float* Wk  = (const float*)d_in[4];
  const float* bk  = (const float*)d_in[5];
  const float* Wv  = (const float*)d_in[6];
  const float* bv  = (const float*)d_in[7];
  const float* Wo  = (const float*)d_in[8];
  const float* bo  = (const float*)d_in[9];
  float* out = (float*)d_out;

  const size_t NTOK = (size_t)MTOT * D_MODEL; // 8M elems
  const size_t WSZ = (size_t)D_MODEL * D_MODEL;
  u16* xb  = (u16*)d_ws;       // x bf16; later reused as attention output
  u16* cb  = xb + NTOK;
  u16* wqb = cb + NTOK;
  u16* wkb = wqb + WSZ;
  u16* wvb = wkb + WSZ;
  u16* wob = wvb + WSZ;
  u16* Qb  = wob + WSZ;
  u16* Kb  = Qb + NTOK;
  u16* Vtb = Kb + NTOK;        // [b*16+h][dh][tok]
  (void)in_sizes; (void)n_in; (void)out_size; (void)ws_size;

  dim3 blk(256);
  cvt_f32_bf16<<<2048, blk, 0, stream>>>(x, xb, (int)(NTOK / 4));
  cvt_f32_bf16<<<2048, blk, 0, stream>>>(ctx, cb, (int)(NTOK / 4));
  cvt_f32_bf16<<<512, blk, 0, stream>>>(Wq, wqb, (int)(WSZ / 4));
  cvt_f32_bf16<<<512, blk, 0, stream>>>(Wk, wkb, (int)(WSZ / 4));
  cvt_f32_bf16<<<512, blk, 0, stream>>>(Wv, wvb, (int)(WSZ / 4));
  cvt_f32_bf16<<<512, blk, 0, stream>>>(Wo, wob, (int)(WSZ / 4));

  gemm_bt<0><<<512, blk, 0, stream>>>(xb, wqb, bq, Qb, MTOT, D_MODEL, D_MODEL);
  gemm_bt<0><<<512, blk, 0, stream>>>(cb, wkb, bk, Kb, MTOT, D_MODEL, D_MODEL);
  gemm_bt<2><<<512, blk, 0, stream>>>(cb, wvb, bv, Vtb, MTOT, D_MODEL, D_MODEL);

  qknorm<<<1024, blk, 0, stream>>>(Qb, MTOT * NHEAD);
  qknorm<<<1024, blk, 0, stream>>>(Kb, MTOT * NHEAD);

  attn_kernel<<<dim3(16, 64), blk, 0, stream>>>(Qb, Kb, Vtb, xb);

  gemm_bt<1><<<512, blk, 0, stream>>>(xb, wob, bo, out, MTOT, D_MODEL, D_MODEL);
}

// Round 3
// 213.128 us; speedup vs baseline: 1.6319x; 1.1797x over previous
//
#include <hip/hip_runtime.h>

typedef unsigned short u16;
typedef unsigned int u32;
typedef __attribute__((ext_vector_type(8))) short bf16x8;
typedef __attribute__((ext_vector_type(4))) float f32x4;
typedef __attribute__((ext_vector_type(16))) float f32x16;
typedef __attribute__((ext_vector_type(4))) u32 u32x4;

#define D_MODEL 1024
#define NHEAD 16
#define DHEAD 64
#define SEQ 2048
#define BATCH 4
#define MTOT (BATCH * SEQ) /* 8192 */

#define MFMA16(A, B, C) __builtin_amdgcn_mfma_f32_16x16x32_bf16((A), (B), (C), 0, 0, 0)
#define MFMA32(A, B, C) __builtin_amdgcn_mfma_f32_32x32x16_bf16((A), (B), (C), 0, 0, 0)

__device__ __forceinline__ u16 f2bf(float f) {
  u32 u = __builtin_bit_cast(u32, f);
  u = (u + 0x7FFFu + ((u >> 16) & 1u)) >> 16;
  return (u16)u;
}
__device__ __forceinline__ float bf2f(u16 h) {
  u32 u = ((u32)h) << 16;
  return __builtin_bit_cast(float, u);
}

// async global->LDS, 16B per lane. lds must be wave-uniform; g is per-lane.
__device__ __forceinline__ void async_copy16(void* lds, const void* g) {
  __builtin_amdgcn_global_load_lds(
      (const __attribute__((address_space(1))) u32*)g,
      (__attribute__((address_space(3))) u32*)lds, 16, 0, 0);
}

__device__ __forceinline__ u32 cvtpk_bf16(float lo, float hi) {
  u32 r;
  asm("v_cvt_pk_bf16_f32 %0, %1, %2" : "=v"(r) : "v"(lo), "v"(hi));
  return r;
}
// swaps a.hi32lanes <-> b.lo32lanes
__device__ __forceinline__ void permswap(u32& a, u32& b) {
  asm("v_permlane32_swap_b32 %0, %1" : "+v"(a), "+v"(b));
}

// ---------------- fp32 -> bf16 convert ----------------
__global__ void cvt_f32_bf16(const float* __restrict__ s, u16* __restrict__ d, int n4) {
  int i = blockIdx.x * blockDim.x + threadIdx.x;
  int st = gridDim.x * blockDim.x;
  for (; i < n4; i += st) {
    float4 v = ((const float4*)s)[i];
    ushort4 o;
    o.x = f2bf(v.x); o.y = f2bf(v.y); o.z = f2bf(v.z); o.w = f2bf(v.w);
    ((ushort4*)d)[i] = o;
  }
}

// ---------------- NT GEMM: C[m][n] = sum_k A[m][k]*B[n][k] + bias[n] ----------------
// SM: 1 = f32 row-major out, 2 = bf16 transposed V out, 3 = bf16 + qk-norm (per 64-col head)
#define BM 128
#define BN 128
#define BKG 64

template <int SM>
__global__ __launch_bounds__(256, 2) void gemm_bt(const u16* __restrict__ A,
                                                  const u16* __restrict__ Bw,
                                                  const float* __restrict__ bias,
                                                  void* __restrict__ Cout,
                                                  int M, int N, int K) {
  __shared__ u16 As[BM * BKG]; // 16KB, rows 128B, granule-swizzled g^=(row&7)
  __shared__ u16 Bs[BN * BKG]; // 16KB
  const int tid = threadIdx.x;
  const int l = tid & 63;
  const int wid = tid >> 6;
  const int nwg = gridDim.x;
  const int bid = blockIdx.x;
  const int cpx = nwg >> 3;
  const int swz = (bid & 7) * cpx + (bid >> 3);
  const int ntile = N / BN;
  const int m0 = (swz / ntile) * BM;
  const int n0 = (swz % ntile) * BN;
  const int wr = wid >> 1, wc = wid & 1;
  const int r = l & 15, kg = l >> 4;
  f32x4 acc[4][4] = {};
  char* AsB = (char*)As;
  char* BsB = (char*)Bs;
  const int arow = l >> 3;
  const int agran = (l & 7) ^ arow;

  for (int kt = 0; kt < K; kt += BKG) {
#pragma unroll
    for (int cc = 0; cc < 4; ++cc) {
      int c = wid + (cc << 2);
      int rowi = (c << 3) + arow;
      const char* ga = (const char*)A + ((size_t)(m0 + rowi) * K + kt) * 2 + agran * 16;
      async_copy16(AsB + c * 1024, ga);
      const char* gb = (const char*)Bw + ((size_t)(n0 + rowi) * K + kt) * 2 + agran * 16;
      async_copy16(BsB + c * 1024, gb);
    }
    __syncthreads();
#pragma unroll
    for (int half = 0; half < 2; ++half) {
      const int g = ((half << 2) + kg) ^ (r & 7);
      bf16x8 af[4], bf[4];
#pragma unroll
      for (int i = 0; i < 4; ++i) {
        af[i] = *(const bf16x8*)(AsB + (wr * 64 + i * 16 + r) * 128 + g * 16);
        bf[i] = *(const bf16x8*)(BsB + (wc * 64 + i * 16 + r) * 128 + g * 16);
      }
#pragma unroll
      for (int i = 0; i < 4; ++i)
#pragma unroll
        for (int j = 0; j < 4; ++j)
          acc[i][j] = MFMA16(af[i], bf[j], acc[i][j]);
    }
    __syncthreads();
  }

  if (SM == 3) {
    // bf16 out + L2-normalize each row's 64-col head group (wave owns exactly one head)
    u16* C = (u16*)Cout;
    float bvj[4];
#pragma unroll
    for (int j = 0; j < 4; ++j) bvj[j] = bias[n0 + wc * 64 + j * 16 + r];
#pragma unroll
    for (int i = 0; i < 4; ++i) {
      const int row0 = m0 + wr * 64 + i * 16 + kg * 4;
#pragma unroll
      for (int jj = 0; jj < 4; ++jj) {
        float t[4];
        float s2 = 0.f;
#pragma unroll
        for (int j = 0; j < 4; ++j) {
          t[j] = acc[i][j][jj] + bvj[j];
          s2 += t[j] * t[j];
        }
        s2 += __shfl_xor(s2, 1);
        s2 += __shfl_xor(s2, 2);
        s2 += __shfl_xor(s2, 4);
        s2 += __shfl_xor(s2, 8);
        const float inv = 1.0f / (sqrtf(s2) + 1e-6f);
#pragma unroll
        for (int j = 0; j < 4; ++j)
          C[(size_t)(row0 + jj) * N + n0 + wc * 64 + j * 16 + r] = f2bf(t[j] * inv);
      }
    }
    return;
  }

#pragma unroll
  for (int i = 0; i < 4; ++i) {
#pragma unroll
    for (int j = 0; j < 4; ++j) {
      const int col = n0 + wc * 64 + j * 16 + r;
      const float bv = bias[col];
      const int row0 = m0 + wr * 64 + i * 16 + kg * 4;
      if (SM == 1) {
        float* C = (float*)Cout;
#pragma unroll
        for (int jj = 0; jj < 4; ++jj)
          C[(size_t)(row0 + jj) * N + col] = acc[i][j][jj] + bv;
      } else {
        // V transposed store: Vt[(b*16+h)*64 + dh][tok], 4 consecutive tok per lane
        u16* C = (u16*)Cout;
        const int hh = col >> 6, dh = col & 63;
        const int bb = row0 >> 11, tok = row0 & 2047;
        ushort4 o;
        o.x = f2bf(acc[i][j][0] + bv);
        o.y = f2bf(acc[i][j][1] + bv);
        o.z = f2bf(acc[i][j][2] + bv);
        o.w = f2bf(acc[i][j][3] + bv);
        *(ushort4*)(C + ((size_t)((bb * 16 + hh) * 64 + dh) * SEQ + tok)) = o;
      }
    }
  }
}

// ---------------- flash attention v3: KVB=64, 4 blocks/CU, conflict-free swizzle ----------------
// block = 4 waves; wave owns 32 q rows, KVB=64 per tile, 32 tiles, double-buffered.
// Fixed softmax max = 1 (post qk-norm S in [-1,1]); in-register P via cvt_pk+permlane32_swap.
// K LDS [64][64] rows 128B; Vt LDS [64][64] rows 128B. granule p = q ^ ((row^(row>>3))&7)
// -> every 8-lane run covers all 8 granules: conflict-free ds_read_b128.
#define KVB 64
#define NT (SEQ / KVB)

__global__ __launch_bounds__(256, 4) void attn_kernel(const u16* __restrict__ Q,
                                                      const u16* __restrict__ K,
                                                      const u16* __restrict__ Vt,
                                                      u16* __restrict__ O) {
  __shared__ alignas(16) u16 Ks[2][KVB * 64]; // 2 x 8KB
  __shared__ alignas(16) u16 Vs[2][64 * KVB]; // 2 x 8KB
  const int tid = threadIdx.x;
  const int l = tid & 63;
  const int wid = tid >> 6;
  const int qg = l & 31;     // q row within wave
  const int half = l >> 5;
  // XCD-chunked grid: each XCD gets 128 consecutive swz = 8 bh values (K/V L2-resident)
  const int bid = blockIdx.x;
  const int swz = (bid & 7) * 128 + (bid >> 3);
  const int qt = swz & 15;   // 0..15
  const int bh = swz >> 4;   // 0..63
  const int b = bh >> 4, h = bh & 15;

  // Q fragments: B-operand, col=q=l&31, k = dc*16 + half*8 + e
  bf16x8 qf[4];
  {
    const u16* q0 = Q + ((size_t)(b * SEQ + qt * 128 + wid * 32 + qg)) * D_MODEL + h * 64 + half * 8;
#pragma unroll
    for (int dc = 0; dc < 4; ++dc) qf[dc] = *(const bf16x8*)(q0 + dc * 16);
  }
  f32x16 oacc[2] = {};
  float lrun = 0.f;

  auto stage = [&](int bufi, int t) {
    const int kv0 = t * KVB;
    char* KsB = (char*)Ks[bufi];
    char* VsB = (char*)Vs[bufi];
    const int rowin = l >> 3;
    const int slot = l & 7;
#pragma unroll
    for (int cc = 0; cc < 4; ++cc) {
      int c = wid + (cc << 2); // 0..15: 0-7 = K chunks, 8-15 = V chunks
      if (c < 8) {
        int row = (c << 3) + rowin; // kv row 0..63
        int q = slot ^ ((row ^ (row >> 3)) & 7);
        const char* g = (const char*)K +
                        ((size_t)(b * SEQ + kv0 + row) * D_MODEL + h * 64 + q * 8) * 2;
        async_copy16(KsB + c * 1024, g);
      } else {
        int row = ((c - 8) << 3) + rowin; // dh row 0..63
        int q = slot ^ ((row ^ (row >> 3)) & 7);
        const char* g = (const char*)Vt +
                        ((size_t)(bh * 64 + row) * SEQ + kv0 + q * 8) * 2;
        async_copy16(VsB + (c - 8) * 1024, g);
      }
    }
  };

  stage(0, 0);
  __syncthreads();
  int buf = 0;

  for (int t = 0; t < NT; ++t) {
    if (t + 1 < NT) stage(buf ^ 1, t + 1);
    const char* KsB = (const char*)Ks[buf];
    const char* VsB = (const char*)Vs[buf];

    // S^T[kv][q]: 2 tiles of 32 kv; lane holds q=l&31, kv=(reg&3)+8*(reg>>2)+4*half (+32*t32)
    f32x16 st[2] = {};
    __builtin_amdgcn_s_setprio(1);
#pragma unroll
    for (int t32 = 0; t32 < 2; ++t32) {
      const int rowK = t32 * 32 + qg;
      const int swk = (rowK ^ (rowK >> 3)) & 7;
#pragma unroll
      for (int dc = 0; dc < 4; ++dc) {
        const int p = (dc * 2 + half) ^ swk;
        bf16x8 kf = *(const bf16x8*)(KsB + rowK * 128 + p * 16);
        st[t32] = MFMA32(kf, qf[dc], st[t32]);
      }
    }
    __builtin_amdgcn_s_setprio(0);

    // softmax with fixed max = 1: p = exp2(s*log2e - log2e)
    float rs = 0.f;
#pragma unroll
    for (int t32 = 0; t32 < 2; ++t32)
#pragma unroll
      for (int rr = 0; rr < 16; ++rr) {
        float z = __builtin_fmaf(st[t32][rr], 1.4426950408889634f, -1.4426950408889634f);
        float pv = __builtin_amdgcn_exp2f(z);
        st[t32][rr] = pv;
        rs += pv;
      }
    lrun += rs;

    // PV: O^T[dh][q] += V^T[dh][kv] * P[q][kv]
#pragma unroll
    for (int t32 = 0; t32 < 2; ++t32) {
#pragma unroll
      for (int cc = 0; cc < 2; ++cc) {
        const int base = cc * 8;
        u32 wA = cvtpk_bf16(st[t32][base + 0], st[t32][base + 1]);
        u32 wB = cvtpk_bf16(st[t32][base + 2], st[t32][base + 3]);
        u32 wC = cvtpk_bf16(st[t32][base + 4], st[t32][base + 5]);
        u32 wD = cvtpk_bf16(st[t32][base + 6], st[t32][base + 7]);
        permswap(wA, wC);
        permswap(wB, wD);
        u32x4 pw = {wA, wB, wC, wD};
        bf16x8 pf = __builtin_bit_cast(bf16x8, pw);
        const int qw = ((t32 * 2 + cc) << 1) + half; // V granule wanted
        __builtin_amdgcn_s_setprio(1);
#pragma unroll
        for (int dt = 0; dt < 2; ++dt) {
          const int rowV = dt * 32 + qg;
          const int pp = qw ^ ((rowV ^ (rowV >> 3)) & 7);
          bf16x8 vf = *(const bf16x8*)(VsB + rowV * 128 + pp * 16);
          oacc[dt] = MFMA32(vf, pf, oacc[dt]);
        }
        __builtin_amdgcn_s_setprio(0);
      }
    }
    __syncthreads();
    buf ^= 1;
  }

  // epilogue: denom = own-half sum + other-half sum; pack pairs, u32 stores
  lrun += __shfl_xor(lrun, 32);
  const float inv = 1.0f / lrun;
  u32* orow = (u32*)(O + ((size_t)(b * SEQ + qt * 128 + wid * 32 + qg)) * D_MODEL + h * 64);
#pragma unroll
  for (int dt = 0; dt < 2; ++dt)
#pragma unroll
    for (int w = 0; w < 8; ++w) {
      const int dh = dt * 32 + (w & 1) * 2 + 8 * (w >> 1) + 4 * half;
      u32 pk = cvtpk_bf16(oacc[dt][2 * w] * inv, oacc[dt][2 * w + 1] * inv);
      orow[dh >> 1] = pk;
    }
}

// ---------------- launch ----------------
extern "C" void kernel_launch(void* const* d_in, const int* in_sizes, int n_in,
                              void* d_out, int out_size, void* d_ws, size_t ws_size,
                              hipStream_t stream) {
  const float* x   = (const float*)d_in[0];
  const float* ctx = (const float*)d_in[1];
  const float* Wq  = (const float*)d_in[2];
  const float* bq  = (const float*)d_in[3];
  const float* Wk  = (const float*)d_in[4];
  const float* bk  = (const float*)d_in[5];
  const float* Wv  = (const float*)d_in[6];
  const float* bv  = (const float*)d_in[7];
  const float* Wo  = (const float*)d_in[8];
  const float* bo  = (const float*)d_in[9];
  float* out = (float*)d_out;

  const size_t NTOK = (size_t)MTOT * D_MODEL; // 8M elems
  const size_t WSZ = (size_t)D_MODEL * D_MODEL;
  u16* xb  = (u16*)d_ws;       // x bf16; later reused as attention output
  u16* cb  = xb + NTOK;
  u16* wqb = cb + NTOK;
  u16* wkb = wqb + WSZ;
  u16* wvb = wkb + WSZ;
  u16* wob = wvb + WSZ;
  u16* Qb  = wob + WSZ;
  u16* Kb  = Qb + NTOK;
  u16* Vtb = Kb + NTOK;        // [b*16+h][dh][tok]
  (void)in_sizes; (void)n_in; (void)out_size; (void)ws_size;

  dim3 blk(256);
  cvt_f32_bf16<<<2048, blk, 0, stream>>>(x, xb, (int)(NTOK / 4));
  cvt_f32_bf16<<<2048, blk, 0, stream>>>(ctx, cb, (int)(NTOK / 4));
  cvt_f32_bf16<<<512, blk, 0, stream>>>(Wq, wqb, (int)(WSZ / 4));
  cvt_f32_bf16<<<512, blk, 0, stream>>>(Wk, wkb, (int)(WSZ / 4));
  cvt_f32_bf16<<<512, blk, 0, stream>>>(Wv, wvb, (int)(WSZ / 4));
  cvt_f32_bf16<<<512, blk, 0, stream>>>(Wo, wob, (int)(WSZ / 4));

  gemm_bt<3><<<512, blk, 0, stream>>>(xb, wqb, bq, Qb, MTOT, D_MODEL, D_MODEL);
  gemm_bt<3><<<512, blk, 0, stream>>>(cb, wkb, bk, Kb, MTOT, D_MODEL, D_MODEL);
  gemm_bt<2><<<512, blk, 0, stream>>>(cb, wvb, bv, Vtb, MTOT, D_MODEL, D_MODEL);

  attn_kernel<<<1024, blk, 0, stream>>>(Qb, Kb, Vtb, xb);

  gemm_bt<1><<<512, blk, 0, stream>>>(xb, wob, bo, out, MTOT, D_MODEL, D_MODEL);
}